// Round 5
// baseline (93.794 us; speedup 1.0000x reference)
//
#include <hip/hip_runtime.h>

// Inv2d: B=4, C=128, H=W=64, G=8 (16 ch/grp), K=7, dil=2, pad=6,
// reduce 128->32, span 32->392.
//
// Round 16: single-kernel fusion. Proof from R2 counters: both kernels
// were <=41.7us while dur read 94.2 -> dur includes big non-kernel time;
// kernel boundaries are expensive. red's consumer is block-local (block
// (b,g,hp) needs red only at its own 128 px), so fold red into the main
// kernel: each wave computes 64px x 16outs in fp32 (identical accumulation
// order + RNE bf16 round => bit-identical results), stages to LDS, then
// ker-MFMA + apply as before. Deletes red_gen launch + red_bf round-trip;
// cost is 8x-duplicated red VALU (~2048 fma/thread, ~2.4us/CU, overlapped).

#define HW 4096   // 64*64
#define NC 128
#define NR 32
#define KK 49
#define KSTR 136  // apply-loop LDS per-tap stride (2 rows x 68)

typedef __attribute__((ext_vector_type(8))) short short8;
typedef __attribute__((ext_vector_type(4))) float f32x4;

__device__ __forceinline__ unsigned short f2bf(float f) {
  unsigned int u = __float_as_uint(f);
  u = (u + 0x7fffu + ((u >> 16) & 1u)) >> 16;   // RNE
  return (unsigned short)u;
}

// ---------------------------------------------------------------- inv_one
__global__ __launch_bounds__(256) void inv_one(
    const float* __restrict__ x, const float* __restrict__ w_reduce,
    const float* __restrict__ b_reduce, const float* __restrict__ w_span,
    const float* __restrict__ b_span, float* __restrict__ out) {
  // grid: 1024 = hpair(32) x g(8) x b(4), XCD-swizzled: each XCD owns 4
  // contiguous (b,g) slices of one batch -> x slice (2 MB) stays L2-hot.
  // Phase 0: red[32][128px] in fp32 (bit-identical to old red_gen).
  // Phase 1: 4 waves compute ker[49][128px] via MFMA into kvs (fp32).
  // Phase 2: apply loop reading x directly (row skip + col masking).
  __shared__ float kvs[KK * KSTR];          // 26.7 KB
  __shared__ short wlds[64 * NR];           // bf16 W tile, 4 KB
  __shared__ float bsl[64];
  __shared__ unsigned short redl[128 * NR]; // bf16 red^T tile, 8 KB

  int orig = blockIdx.x;
  int blk = (orig & 7) * 128 + (orig >> 3);   // bijective: 1024 % 8 == 0
  int hp = blk & 31;
  int g = (blk >> 5) & 7;
  int b = blk >> 8;
  int tid = threadIdx.x;
  int h0 = hp * 2;
  int p0 = h0 * 64;                  // this block's 128-px slice

  // ---- stage W_g (fp32 -> bf16) + bias into LDS ----
  const float* wg = w_span + g * KK * NR;            // 1568 floats
#pragma unroll
  for (int it = 0; it < 8; ++it) {
    int idx = it * 256 + tid;
    wlds[idx] = (idx < KK * NR) ? (short)f2bf(wg[idx]) : (short)0;
  }
  if (tid < 64) bsl[tid] = (tid < KK) ? b_span[g * KK + tid] : 0.f;

  int l = tid & 63;
  int wv = __builtin_amdgcn_readfirstlane(tid >> 6);  // wave id 0..3
  int quad = l >> 4;
  int mn = l & 15;

  // ---- phase 0: red for this block's 128 px ----
  // wave wv: px-half (wv&1), out-16-block (wv>>1). fp32 acc, k ascending,
  // RNE round -> bit-identical to the old standalone red_gen.
  {
    int ob = (wv >> 1) * 16;                 // wave-uniform out base
    int pl = (wv & 1) * 64 + l;              // local px 0..127
    const float* wq = w_reduce + ob * NC;    // scalar (s_load) base
    const float* xpx = x + (size_t)b * NC * HW + p0 + pl;

    float acc[16];
#pragma unroll
    for (int j = 0; j < 16; ++j) acc[j] = b_reduce[ob + j];

#pragma unroll 4
    for (int k = 0; k < NC; ++k) {
      float xk = xpx[(size_t)k * HW];
#pragma unroll
      for (int j = 0; j < 16; ++j) acc[j] = fmaf(xk, wq[j * NC + k], acc[j]);
    }

    union { short8 v; unsigned short u[8]; } pk0, pk1;
#pragma unroll
    for (int j = 0; j < 8; ++j) { pk0.u[j] = f2bf(acc[j]); pk1.u[j] = f2bf(acc[8 + j]); }
    *(short8*)(&redl[pl * NR + ob]) = pk0.v;
    *(short8*)(&redl[pl * NR + ob + 8]) = pk1.v;
  }
  __syncthreads();

  // ---- phase 1: ker = W x red^T via MFMA ----
  // A-fragments: A[m=lane&15][k=quad*8+j] (same mapping as proven ker_gen)
  short8 af[4];
#pragma unroll
  for (int tt = 0; tt < 4; ++tt)
    af[tt] = *(const short8*)(&wlds[(tt * 16 + mn) * NR + quad * 8]);

  // bias as MFMA C-operand: C/D row = quad*4+reg, col = lane&15
  f32x4 ci[4];
#pragma unroll
  for (int tt = 0; tt < 4; ++tt) {
#pragma unroll
    for (int r = 0; r < 4; ++r) ci[tt][r] = bsl[tt * 16 + quad * 4 + r];
  }

  // wave wv covers px [wv*32, +32) in 2 n-tiles of 16 px (B from redl LDS)
  const unsigned short* rl = &redl[(wv * 32 + mn) * NR + quad * 8];
#pragma unroll
  for (int nt = 0; nt < 2; ++nt) {
    short8 bf = *(const short8*)(rl + nt * 16 * NR);
    f32x4 d0 = __builtin_amdgcn_mfma_f32_16x16x32_bf16(af[0], bf, ci[0], 0, 0, 0);
    f32x4 d1 = __builtin_amdgcn_mfma_f32_16x16x32_bf16(af[1], bf, ci[1], 0, 0, 0);
    f32x4 d2 = __builtin_amdgcn_mfma_f32_16x16x32_bf16(af[2], bf, ci[2], 0, 0, 0);
    f32x4 d3 = __builtin_amdgcn_mfma_f32_16x16x32_bf16(af[3], bf, ci[3], 0, 0, 0);
    int pxl = wv * 32 + nt * 16 + mn;          // 0..127 (r is wave-uniform)
    int r = pxl >> 6, col = pxl & 63;
    float* dst = &kvs[r * 68 + col];
#pragma unroll
    for (int rg = 0; rg < 4; ++rg) {
      dst[(size_t)(0 * 16 + quad * 4 + rg) * KSTR] = d0[rg];
      dst[(size_t)(1 * 16 + quad * 4 + rg) * KSTR] = d1[rg];
      dst[(size_t)(2 * 16 + quad * 4 + rg) * KSTR] = d2[rg];
    }
    if (quad == 0) dst[(size_t)48 * KSTR] = d3[0];  // only tap 48
  }
  __syncthreads();

  // ---- phase 2: apply, reading x directly ----
  int c = tid >> 4;                  // channel in group
  int sub = tid & 15;
  int r = sub >> 3;                  // row 0..1
  int oct = sub & 7;                 // col octet

  // xr[t] holds col (8*oct - 8 + t); FMAs use xr[2..21] (cols 8oct-6..+13)
  const float* xc = x + ((size_t)(b * NC + g * 16 + c)) * HW + 8 * oct - 8;
  // redirect discarded float4 loads (oct 0: cols<0, oct 7: cols>=64) to
  // safe in-row addresses; their xr slots are zeroed below.
  int mo0 = 0, mo1 = 4, mo4 = 16, mo5 = 20;
  if (oct == 0) { mo0 = 8; mo1 = 12; }
  if (oct == 7) { mo4 = 8; mo5 = 12; }

  float2 a0 = {0.f, 0.f}, a1 = {0.f, 0.f}, a2 = {0.f, 0.f}, a3 = {0.f, 0.f};

#pragma unroll
  for (int i = 0; i < 7; ++i) {
    int rbase = h0 + 2 * i - 6;            // even; rows rbase, rbase+1
    if (rbase < 0 || rbase > 62) continue; // wave-uniform row skip
    const float* pr = xc + (size_t)(rbase + r) * 64;
    float xr[24];
    float4 v;
    v = *(const float4*)(pr + mo0); xr[0]=v.x; xr[1]=v.y; xr[2]=v.z; xr[3]=v.w;
    v = *(const float4*)(pr + mo1); xr[4]=v.x; xr[5]=v.y; xr[6]=v.z; xr[7]=v.w;
    v = *(const float4*)(pr + 8);   xr[8]=v.x; xr[9]=v.y; xr[10]=v.z; xr[11]=v.w;
    v = *(const float4*)(pr + 12);  xr[12]=v.x; xr[13]=v.y; xr[14]=v.z; xr[15]=v.w;
    v = *(const float4*)(pr + mo4); xr[16]=v.x; xr[17]=v.y; xr[18]=v.z; xr[19]=v.w;
    v = *(const float4*)(pr + mo5); xr[20]=v.x; xr[21]=v.y; xr[22]=v.z; xr[23]=v.w;
    if (oct == 0) { xr[2]=0.f; xr[3]=0.f; xr[4]=0.f; xr[5]=0.f; xr[6]=0.f; xr[7]=0.f; }
    if (oct == 7) { xr[16]=0.f; xr[17]=0.f; xr[18]=0.f; xr[19]=0.f; xr[20]=0.f; xr[21]=0.f; }
#pragma unroll
    for (int j = 0; j < 7; ++j) {
      const float* kb = &kvs[(i * 7 + j) * KSTR + r * 68 + 8 * oct];
      float4 k0 = *(const float4*)(kb);
      float4 k1 = *(const float4*)(kb + 4);
      a0.x = fmaf(xr[2 + 2 * j], k0.x, a0.x);
      a0.y = fmaf(xr[3 + 2 * j], k0.y, a0.y);
      a1.x = fmaf(xr[4 + 2 * j], k0.z, a1.x);
      a1.y = fmaf(xr[5 + 2 * j], k0.w, a1.y);
      a2.x = fmaf(xr[6 + 2 * j], k1.x, a2.x);
      a2.y = fmaf(xr[7 + 2 * j], k1.y, a2.y);
      a3.x = fmaf(xr[8 + 2 * j], k1.z, a3.x);
      a3.y = fmaf(xr[9 + 2 * j], k1.w, a3.y);
    }
  }

  int h = h0 + r;
  float* op = out + (size_t)(b * NC + g * 16 + c) * HW + h * 64 + 8 * oct;
  *(float4*)op = make_float4(a0.x, a0.y, a1.x, a1.y);
  *(float4*)(op + 4) = make_float4(a2.x, a2.y, a3.x, a3.y);
}

extern "C" void kernel_launch(void* const* d_in, const int* in_sizes, int n_in,
                              void* d_out, int out_size, void* d_ws, size_t ws_size,
                              hipStream_t stream) {
  const float* x        = (const float*)d_in[0];  // [4,128,64,64]
  const float* w_reduce = (const float*)d_in[1];  // [32,128]
  const float* b_reduce = (const float*)d_in[2];  // [32]
  const float* w_span   = (const float*)d_in[3];  // [392,32]
  const float* b_span   = (const float*)d_in[4];  // [392]
  float* out = (float*)d_out;                     // [4,128,64,64]

  inv_one<<<1024, 256, 0, stream>>>(x, w_reduce, b_reduce, w_span, b_span, out);
}

// Round 6
// 86.019 us; speedup vs baseline: 1.0904x; 1.0904x over previous
//
#include <hip/hip_runtime.h>

// Inv2d: B=4, C=128, H=W=64, G=8 (16 ch/grp), K=7, dil=2, pad=6,
// reduce 128->32, span 32->392.
//
// Round 17: revert R5's fused-red regression (8x duplicated red cost +8us;
// separate red_gen is ~2-3us). Back to R4 two-kernel structure, with ONE
// change: kvs stored as bf16 (ker values are bf16-MFMA-rounded anyway;
// proven absmax-neutral in the old R11 global-bf16-ker variant).
//  - apply per-tap read: one ds_read_b128 (8 bf16) instead of two -> LDS
//    instructions halve (98 -> 49/thread, 401K -> 200K total).
//  - LDS 31 -> 18.5 KB -> +1-2 blocks/CU if VGPR allows.
// This is also the T-LDS vs T-L2 discriminating experiment: a win means
// apply was LDS-issue-bound; neutral means L2-BW-bound (next: stage x).

#define HW 4096   // 64*64
#define NC 128
#define NR 32
#define KK 49
#define KSB 144   // bf16 elems per tap: 2 rows x 72 (pad 64->72, 16B-align)

typedef __attribute__((ext_vector_type(8))) short short8;
typedef __attribute__((ext_vector_type(4))) float f32x4;

__device__ __forceinline__ unsigned short f2bf(float f) {
  unsigned int u = __float_as_uint(f);
  u = (u + 0x7fffu + ((u >> 16) & 1u)) >> 16;   // RNE
  return (unsigned short)u;
}
__device__ __forceinline__ float bf2f(unsigned short u) {
  return __uint_as_float(((unsigned int)u) << 16);
}

// ---------------------------------------------------------------- red_gen
__global__ __launch_bounds__(256) void red_gen(
    const float* __restrict__ x, const float* __restrict__ w_reduce,
    const float* __restrict__ b_reduce, unsigned short* __restrict__ red_bf) {
  // grid: 512 = b(4) x row(64) x ohalf(2). Block: one 64-px row, 16 of 32
  // outputs. Both ohalf blocks stage the same row (2nd read is L2 hit).
  __shared__ float xs[NC][64];       // 32 KB
  int t = threadIdx.x;
  int blk = blockIdx.x;
  int b = blk >> 7;
  int sub = blk & 127;               // row(6b) | ohalf(1b)
  int row = sub >> 1;
  int oh = sub & 1;
  int p0 = row * 64;

  const float* xb = x + b * NC * HW + p0;
  int fx = t & 15;
  int c0 = t >> 4;
#pragma unroll
  for (int r = 0; r < 8; ++r) {
    int c = c0 + 16 * r;
    *(float4*)(&xs[c][fx * 4]) = *(const float4*)(xb + c * HW + fx * 4);
  }
  __syncthreads();

  int px = t & 63;
  int wv = __builtin_amdgcn_readfirstlane(t >> 6);  // wave id 0..3
  int ob = oh * 16 + wv * 4;                        // wave-uniform out base
  const float* wq = w_reduce + ob * NC;             // scalar (s_load) base

  float acc[4];
#pragma unroll
  for (int j = 0; j < 4; ++j) acc[j] = b_reduce[ob + j];

#pragma unroll 8
  for (int k = 0; k < NC; ++k) {
    float xk = xs[k][px];
#pragma unroll
    for (int j = 0; j < 4; ++j) acc[j] += xk * wq[j * NC + k];
  }

  // red^T bf16: [b][px][32 o], one 8B store (o-quad = ob..ob+3)
  union { unsigned long long v; unsigned short u[4]; } pk;
#pragma unroll
  for (int j = 0; j < 4; ++j) pk.u[j] = f2bf(acc[j]);
  *(unsigned long long*)(red_bf + ((size_t)(b * HW) + p0 + px) * NR + ob) = pk.v;
}

// ---------------------------------------------------------------- inv_fused
__global__ __launch_bounds__(256) void inv_fused(
    const float* __restrict__ x, const unsigned short* __restrict__ red_bf,
    const float* __restrict__ w_span, const float* __restrict__ b_span,
    float* __restrict__ out) {
  // grid: 1024 = hpair(32) x g(8) x b(4), XCD-swizzled: each XCD owns 4
  // contiguous (b,g) slices -> x slice stays L2-hot.
  // Phase 1: 4 waves compute ker[49][128px] via MFMA -> kvs_bf (bf16).
  // Phase 2: apply loop reading x directly (row skip + col masking).
  __shared__ unsigned short kvs_bf[KK * KSB];  // 13.8 KB
  __shared__ short wlds[64 * NR];              // bf16 W tile, 4 KB
  __shared__ float bsl[64];

  int orig = blockIdx.x;
  int blk = (orig & 7) * 128 + (orig >> 3);   // bijective: 1024 % 8 == 0
  int hp = blk & 31;
  int g = (blk >> 5) & 7;
  int b = blk >> 8;
  int tid = threadIdx.x;
  int h0 = hp * 2;
  int p0 = h0 * 64;                  // this block's 128-px slice

  // ---- stage W_g (fp32 -> bf16) + bias into LDS ----
  const float* wg = w_span + g * KK * NR;            // 1568 floats
#pragma unroll
  for (int it = 0; it < 8; ++it) {
    int idx = it * 256 + tid;
    wlds[idx] = (idx < KK * NR) ? (short)f2bf(wg[idx]) : (short)0;
  }
  if (tid < 64) bsl[tid] = (tid < KK) ? b_span[g * KK + tid] : 0.f;
  __syncthreads();

  int l = tid & 63;
  int wv = __builtin_amdgcn_readfirstlane(tid >> 6);  // wave id 0..3
  int quad = l >> 4;
  int mn = l & 15;

  // A-fragments: A[m=lane&15][k=quad*8+j] (same mapping as proven ker_gen)
  short8 af[4];
#pragma unroll
  for (int tt = 0; tt < 4; ++tt)
    af[tt] = *(const short8*)(&wlds[(tt * 16 + mn) * NR + quad * 8]);

  // bias as MFMA C-operand: C/D row = quad*4+reg, col = lane&15
  f32x4 ci[4];
#pragma unroll
  for (int tt = 0; tt < 4; ++tt) {
#pragma unroll
    for (int r = 0; r < 4; ++r) ci[tt][r] = bsl[tt * 16 + quad * 4 + r];
  }

  // wave wv covers px [p0 + wv*32, +32) in 2 n-tiles of 16 px
  const unsigned short* rb =
      red_bf + ((size_t)b * HW + p0 + wv * 32 + mn) * NR + quad * 8;
#pragma unroll
  for (int nt = 0; nt < 2; ++nt) {
    short8 bf = *(const short8*)(rb + (size_t)nt * 16 * NR);
    f32x4 d0 = __builtin_amdgcn_mfma_f32_16x16x32_bf16(af[0], bf, ci[0], 0, 0, 0);
    f32x4 d1 = __builtin_amdgcn_mfma_f32_16x16x32_bf16(af[1], bf, ci[1], 0, 0, 0);
    f32x4 d2 = __builtin_amdgcn_mfma_f32_16x16x32_bf16(af[2], bf, ci[2], 0, 0, 0);
    f32x4 d3 = __builtin_amdgcn_mfma_f32_16x16x32_bf16(af[3], bf, ci[3], 0, 0, 0);
    int pxl = wv * 32 + nt * 16 + mn;          // 0..127 (r is wave-uniform)
    int r = pxl >> 6, col = pxl & 63;
    int base = r * 72 + col;
#pragma unroll
    for (int rg = 0; rg < 4; ++rg) {
      kvs_bf[(0 * 16 + quad * 4 + rg) * KSB + base] = f2bf(d0[rg]);
      kvs_bf[(1 * 16 + quad * 4 + rg) * KSB + base] = f2bf(d1[rg]);
      kvs_bf[(2 * 16 + quad * 4 + rg) * KSB + base] = f2bf(d2[rg]);
    }
    if (quad == 0) kvs_bf[48 * KSB + base] = f2bf(d3[0]);  // only tap 48
  }
  __syncthreads();

  // ---- phase 2: apply, reading x directly ----
  int c = tid >> 4;                  // channel in group
  int sub = tid & 15;
  int r = sub >> 3;                  // row 0..1
  int oct = sub & 7;                 // col octet

  // xr[t] holds col (8*oct - 8 + t); FMAs use xr[2..21] (cols 8oct-6..+13)
  const float* xc = x + ((size_t)(b * NC + g * 16 + c)) * HW + 8 * oct - 8;
  // redirect discarded float4 loads (oct 0: cols<0, oct 7: cols>=64) to
  // safe in-row addresses; their xr slots are zeroed below.
  int mo0 = 0, mo1 = 4, mo4 = 16, mo5 = 20;
  if (oct == 0) { mo0 = 8; mo1 = 12; }
  if (oct == 7) { mo4 = 8; mo5 = 12; }

  float2 a0 = {0.f, 0.f}, a1 = {0.f, 0.f}, a2 = {0.f, 0.f}, a3 = {0.f, 0.f};

#pragma unroll
  for (int i = 0; i < 7; ++i) {
    int rbase = h0 + 2 * i - 6;            // even; rows rbase, rbase+1
    if (rbase < 0 || rbase > 62) continue; // wave-uniform row skip
    const float* pr = xc + (size_t)(rbase + r) * 64;
    float xr[24];
    float4 v;
    v = *(const float4*)(pr + mo0); xr[0]=v.x; xr[1]=v.y; xr[2]=v.z; xr[3]=v.w;
    v = *(const float4*)(pr + mo1); xr[4]=v.x; xr[5]=v.y; xr[6]=v.z; xr[7]=v.w;
    v = *(const float4*)(pr + 8);   xr[8]=v.x; xr[9]=v.y; xr[10]=v.z; xr[11]=v.w;
    v = *(const float4*)(pr + 12);  xr[12]=v.x; xr[13]=v.y; xr[14]=v.z; xr[15]=v.w;
    v = *(const float4*)(pr + mo4); xr[16]=v.x; xr[17]=v.y; xr[18]=v.z; xr[19]=v.w;
    v = *(const float4*)(pr + mo5); xr[20]=v.x; xr[21]=v.y; xr[22]=v.z; xr[23]=v.w;
    if (oct == 0) { xr[2]=0.f; xr[3]=0.f; xr[4]=0.f; xr[5]=0.f; xr[6]=0.f; xr[7]=0.f; }
    if (oct == 7) { xr[16]=0.f; xr[17]=0.f; xr[18]=0.f; xr[19]=0.f; xr[20]=0.f; xr[21]=0.f; }
#pragma unroll
    for (int j = 0; j < 7; ++j) {
      union { short8 v; unsigned short u[8]; } kv;
      kv.v = *(const short8*)(&kvs_bf[(i * 7 + j) * KSB + r * 72 + 8 * oct]);
      a0.x = fmaf(xr[2 + 2 * j], bf2f(kv.u[0]), a0.x);
      a0.y = fmaf(xr[3 + 2 * j], bf2f(kv.u[1]), a0.y);
      a1.x = fmaf(xr[4 + 2 * j], bf2f(kv.u[2]), a1.x);
      a1.y = fmaf(xr[5 + 2 * j], bf2f(kv.u[3]), a1.y);
      a2.x = fmaf(xr[6 + 2 * j], bf2f(kv.u[4]), a2.x);
      a2.y = fmaf(xr[7 + 2 * j], bf2f(kv.u[5]), a2.y);
      a3.x = fmaf(xr[8 + 2 * j], bf2f(kv.u[6]), a3.x);
      a3.y = fmaf(xr[9 + 2 * j], bf2f(kv.u[7]), a3.y);
    }
  }

  int h = h0 + r;
  float* op = out + (size_t)(b * NC + g * 16 + c) * HW + h * 64 + 8 * oct;
  *(float4*)op = make_float4(a0.x, a0.y, a1.x, a1.y);
  *(float4*)(op + 4) = make_float4(a2.x, a2.y, a3.x, a3.y);
}

extern "C" void kernel_launch(void* const* d_in, const int* in_sizes, int n_in,
                              void* d_out, int out_size, void* d_ws, size_t ws_size,
                              hipStream_t stream) {
  const float* x        = (const float*)d_in[0];  // [4,128,64,64]
  const float* w_reduce = (const float*)d_in[1];  // [32,128]
  const float* b_reduce = (const float*)d_in[2];  // [32]
  const float* w_span   = (const float*)d_in[3];  // [392,32]
  const float* b_span   = (const float*)d_in[4];  // [392]
  float* out = (float*)d_out;                     // [4,128,64,64]

  unsigned short* red_bf = (unsigned short*)d_ws;  // 4*4096*32 bf16 = 1 MB

  red_gen<<<512, 256, 0, stream>>>(x, w_reduce, b_reduce, red_bf);
  inv_fused<<<1024, 256, 0, stream>>>(x, red_bf, w_span, b_span, out);
}